// Round 19
// baseline (2742.552 us; speedup 1.0000x reference)
//
#include <hip/hip_runtime.h>
#include <cstddef>

#define NMAT 512
#define MRHS 12

__device__ __forceinline__ float rdlane(float v, int l) {
    return __int_as_float(__builtin_amdgcn_readlane(__float_as_int(v), l));
}

// ---------------- Stage 1: A = LU = constant_part + sum_e r[e] * M[e] ----------------
__global__ void __launch_bounds__(256) k_setup(const float* __restrict__ M,
                                               const float* __restrict__ r,
                                               const float* __restrict__ cpart,
                                               float* __restrict__ A,
                                               float* __restrict__ LU) {
    __shared__ float rs[1024];
    const int tid = threadIdx.x;
    for (int i = tid; i < 1024; i += 256) rs[i] = r[i];
    __syncthreads();
    const int idx2 = blockIdx.x * 256 + tid;          // 0..131071
    const float2* __restrict__ M2 = (const float2*)M;
    float2 a = ((const float2*)cpart)[idx2];
    float ax = a.x, ay = a.y;
#pragma unroll 16
    for (int e = 0; e < 1024; ++e) {
        float2 v = M2[(size_t)e * 131072u + idx2];
        float rv = rs[e];
        ax += rv * v.x; ay += rv * v.y;
    }
    float2 o; o.x = ax; o.y = ay;
    ((float2*)A)[idx2] = o;
    ((float2*)LU)[idx2] = o;
}

// ---------------- mode-0 solve (b = e_{500+c}), blocked, R11/R14-proven ----------------
__device__ __forceinline__ void solve0_f(const float* __restrict__ LUT,
                                         const float* __restrict__ dinv,
                                         float* __restrict__ W, int c, int lane) {
    float y[8];
#pragma unroll
    for (int s = 0; s < 8; ++s) y[s] = 0.f;
    y[7] = (lane == 52 + c) ? 1.0f : 0.0f;
    float Dc[64];
#pragma unroll
    for (int q = 0; q < 64; ++q)
        Dc[q] = LUT[(size_t)(448 + q) * NMAT + 448 + lane];
#pragma unroll 4
    for (int jl = 52; jl < 63; ++jl) {
        float yj = __shfl(y[7], jl);
        if (lane > jl) y[7] -= Dc[jl] * yj;
    }
#pragma unroll
    for (int js = 7; js >= 0; --js) {
        const int base = js * 64;
        float a0 = 0.f, a1 = 0.f;
        for (int s = js + 1; s < 8; ++s) {
#pragma unroll 8
            for (int m = 0; m < 64; m += 2) {
                a0 += LUT[(size_t)(s * 64 + m)     * NMAT + base + lane] * rdlane(y[s], m);
                a1 += LUT[(size_t)(s * 64 + m + 1) * NMAT + base + lane] * rdlane(y[s], m + 1);
            }
        }
        y[js] -= (a0 + a1);
#pragma unroll
        for (int q = 0; q < 64; ++q)
            Dc[q] = LUT[(size_t)(base + q) * NMAT + base + lane];
        float dvb = dinv[base + lane];
#pragma unroll 4
        for (int jl = 63; jl >= 0; --jl) {
            float xj = __shfl(y[js], jl) * rdlane(dvb, jl);
            float t = y[js] - Dc[jl] * xj;
            y[js] = (lane < jl) ? t : ((lane == jl) ? xj : y[js]);
        }
    }
#pragma unroll
    for (int s = 0; s < 8; ++s)
        W[(s * 64 + lane) * MRHS + c] = y[s];
}

// ---------------- NB=128 panel: factor 512x128 panel in ONE dispatch (R14-proven) --------
// launch_bounds(512, 2): 2 waves/EU min -> 256-VGPR budget, no spill for the ~170-reg
// live set (cA[64]+cB[64]+dA[16]+dB[16]).
template <int NR>
__global__ void __launch_bounds__(512, 2) k_panel128(const float* __restrict__ LU,
                                                     float* __restrict__ LUT,
                                                     float* __restrict__ dinvG,
                                                     float* __restrict__ W,
                                                     int k0) {
    constexpr int NG = (NR - 128) / 64;      // L21 row-groups (6,4,2,0)
    __shared__ float pivA[2][64], pivB[2][64];
    __shared__ float U11A[64 * 65];
    __shared__ float U11B[64 * 65];
    __shared__ float U12l[64 * 65];
    __shared__ float L10l[64 * 65];
    __shared__ float dinvL[128];
    const int tid = threadIdx.x, w = tid >> 6, lane = tid & 63;
    const int k1p = k0 + 128;

    // early-issue L21 rows (latency hidden under diag factor)
    float cA[64], cB[64];
    if (NG > 0 && w < NG) {
        const int row = k1p + w * 64 + lane;
#pragma unroll
        for (int c = 0; c < 64; ++c) cA[c] = LU[(size_t)row * NMAT + k0 + c];
#pragma unroll
        for (int c = 0; c < 64; ++c) cB[c] = LU[(size_t)row * NMAT + k0 + 64 + c];
    }
    float dA[16], dB[16];
#pragma unroll
    for (int s = 0; s < 16; ++s) {
        const int row = k0 + s * 8 + w;
        dA[s] = LU[(size_t)row * NMAT + k0 + lane];
        dB[s] = LU[(size_t)row * NMAT + k0 + 64 + lane];
    }
    // ---- left 64 pivots (cols k0..k0+63), rows 0..127 ----
    for (int j = 0; j < 64; ++j) {
        if (w == (j & 7)) {
#pragma unroll
            for (int s = 0; s < 16; ++s)
                if ((j >> 3) == s) {
                    pivA[j & 1][lane] = dA[s];
                    pivB[j & 1][lane] = dB[s];
                    U11A[j * 65 + lane] = dA[s];
                }
        }
        __syncthreads();
        float pvlA = pivA[j & 1][lane], pvlB = pivB[j & 1][lane];
        float pinv = 1.0f / __shfl(pvlA, j);
        if (tid == 0) dinvL[j] = pinv;
#pragma unroll
        for (int s = 0; s < 16; ++s) {
            int i = s * 8 + w;
            if (i > j) {                                  // wave-uniform
                float l = __shfl(dA[s], j) * pinv;
                float updA = dA[s] - l * pvlA;
                dA[s] = (lane > j) ? updA : ((lane == j) ? l : dA[s]);
                dB[s] -= l * pvlB;                        // all 64 right-half cols
            }
        }
    }
    __syncthreads();
    // publish U12 (rows 0..63 of right half) and L10 (rows 64..127 of left half)
#pragma unroll
    for (int s = 0; s < 8; ++s) {
        int i = s * 8 + w;                                // 0..63
        U12l[i * 65 + lane] = dB[s];
        L10l[i * 65 + lane] = dA[s + 8];                  // row 64+i, left half
    }
    __syncthreads();
    // ---- L21 left substitution + Schur on right half ----
    if (NG > 0 && w < NG) {
#pragma unroll
        for (int j = 0; j < 64; ++j) {
            float lj = cA[j] * dinvL[j];
            cA[j] = lj;
            float rowv = U11A[j * 65 + lane];
#pragma unroll
            for (int jj = j + 1; jj < 64; ++jj)
                cA[jj] -= lj * rdlane(rowv, jj);
        }
#pragma unroll
        for (int j = 0; j < 64; ++j) {
            float lj = cA[j];
            float rowv = U12l[j * 65 + lane];
#pragma unroll
            for (int c = 0; c < 64; ++c)
                cB[c] -= lj * rdlane(rowv, c);
        }
    }
    // ---- right 64 pivots (cols k0+64..k0+127), rows 64..127 ----
    for (int j = 64; j < 128; ++j) {
        const int jj = j - 64;
        if (w == (j & 7)) {
#pragma unroll
            for (int s = 8; s < 16; ++s)
                if ((j >> 3) == s) {
                    pivB[j & 1][lane] = dB[s];
                    U11B[jj * 65 + lane] = dB[s];
                }
        }
        __syncthreads();
        float pvlB = pivB[j & 1][lane];
        float pinv = 1.0f / __shfl(pvlB, jj);
        if (tid == 0) dinvL[j] = pinv;
#pragma unroll
        for (int s = 8; s < 16; ++s) {
            int i = s * 8 + w;
            if (i > j) {
                float l = __shfl(dB[s], jj) * pinv;
                float updB = dB[s] - l * pvlB;
                dB[s] = (lane > jj) ? updB : ((lane == jj) ? l : dB[s]);
            }
        }
    }
    __syncthreads();
    // ---- L21 right substitution ----
    if (NG > 0 && w < NG) {
#pragma unroll
        for (int jj = 0; jj < 64; ++jj) {
            float lj = cB[jj] * dinvL[64 + jj];
            cB[jj] = lj;
            float rowv = U11B[jj * 65 + lane];
#pragma unroll
            for (int c = jj + 1; c < 64; ++c)
                cB[c] -= lj * rdlane(rowv, c);
        }
    }
    // ---- writes ----
    if (tid < 128) dinvG[k0 + tid] = dinvL[tid];
#pragma unroll
    for (int q = 0; q < 16; ++q) {
        const int c = w * 16 + q;                        // 0..127
        float v0, v1;
        if (c < 64) { v0 = U11A[lane * 65 + c];        v1 = L10l[lane * 65 + c]; }
        else        { v0 = U12l[lane * 65 + (c - 64)]; v1 = U11B[lane * 65 + (c - 64)]; }
        LUT[(size_t)(k0 + c) * NMAT + k0 + lane]      = v0;   // rows 0..63
        LUT[(size_t)(k0 + c) * NMAT + k0 + 64 + lane] = v1;   // rows 64..127
    }
    if (NG > 0 && w < NG) {
        const int row = k1p + w * 64 + lane;
#pragma unroll
        for (int c = 0; c < 64; ++c)
            LUT[(size_t)(k0 + c) * NMAT + row] = cA[c];
#pragma unroll
        for (int c = 0; c < 64; ++c)
            LUT[(size_t)(k0 + 64 + c) * NMAT + row] = cB[c];
    }
    if (NR == 128) {
        // final panel: LUT complete -> fused mode-0 solves (R14-proven fusion)
        __threadfence_block();
        __syncthreads();
        for (int c = w; c < MRHS; c += 8)
            solve0_f(LUT, dinvG, W, c, lane);
    }
}

// ---------------- NB=128 update: trsm (wave 0) + U12^T or K=128 gemm (R14-proven) --------
// launch_bounds(256, 1): 1 wave/EU -> 512-VGPR budget, wave-0's y[128] stays in regs.
__global__ void __launch_bounds__(256, 1) k_update128(float* __restrict__ LU,
                                                      float* __restrict__ LUT,
                                                      int k0) {
    __shared__ float yLDS[128 * 65];
    __shared__ float sL21[64 * 132];
    const int k1p = k0 + 128;
    const int jc0 = k1p + blockIdx.x * 64;
    const int tid = threadIdx.x, w = tid >> 6, lane = tid & 63;
    const bool urole = (blockIdx.y > 0);
    const int r0 = k1p + ((int)blockIdx.y - 1) * 64;

    float acc[4][4];
    const int trow = tid >> 4, tcol = tid & 15;
    if (urole) {
#pragma unroll
        for (int rr = 0; rr < 4; ++rr) {
            float4 v = *(const float4*)&LU[(size_t)(r0 + 4 * trow + rr) * NMAT + jc0 + 4 * tcol];
            acc[rr][0] = v.x; acc[rr][1] = v.y; acc[rr][2] = v.z; acc[rr][3] = v.w;
        }
        if (w > 0) {   // waves 1..3 stage L21 while wave 0 runs the trsm
            for (int idx = tid - 64; idx < 8192; idx += 192) {
                int kk = idx >> 6, row = idx & 63;
                sL21[row * 132 + kk] = LUT[(size_t)(k0 + kk) * NMAT + r0 + row];
            }
        }
    }
    if (w == 0) {
        // forward substitution, lane = column, y[i] = row i of this column tile
        float y[128];
#pragma unroll
        for (int i = 0; i < 128; ++i)
            y[i] = LU[(size_t)(k0 + i) * NMAT + jc0 + lane];
#pragma unroll
        for (int tc = 0; tc < 8; ++tc) {
            float cvLo[16], cvHi[16];
#pragma unroll
            for (int q = 0; q < 16; ++q) {
                cvLo[q] = LUT[(size_t)(k0 + tc * 16 + q) * NMAT + k0 + lane];
                cvHi[q] = LUT[(size_t)(k0 + tc * 16 + q) * NMAT + k0 + 64 + lane];
            }
#pragma unroll
            for (int q = 0; q < 16; ++q) {
                const int t = tc * 16 + q;
                float yt = y[t];
#pragma unroll
                for (int i = t + 1; i < 128; ++i) {
                    float lij = (i < 64) ? rdlane(cvLo[q], i) : rdlane(cvHi[q], i - 64);
                    y[i] -= lij * yt;
                }
            }
        }
#pragma unroll
        for (int i = 0; i < 128; ++i) yLDS[i * 65 + lane] = y[i];
    }
    __syncthreads();
    if (!urole) {
        for (int idx = tid; idx < 8192; idx += 256) {
            int jc = idx >> 7, i = idx & 127;
            LUT[(size_t)(jc0 + jc) * NMAT + k0 + i] = yLDS[i * 65 + jc];
        }
        return;
    }
#pragma unroll 4
    for (int kk = 0; kk < 128; ++kk) {
        float b0 = yLDS[kk * 65 + 4 * tcol + 0];
        float b1 = yLDS[kk * 65 + 4 * tcol + 1];
        float b2 = yLDS[kk * 65 + 4 * tcol + 2];
        float b3 = yLDS[kk * 65 + 4 * tcol + 3];
#pragma unroll
        for (int rr = 0; rr < 4; ++rr) {
            float a = sL21[(4 * trow + rr) * 132 + kk];
            acc[rr][0] -= a * b0; acc[rr][1] -= a * b1;
            acc[rr][2] -= a * b2; acc[rr][3] -= a * b3;
        }
    }
#pragma unroll
    for (int rr = 0; rr < 4; ++rr) {
        float4 v; v.x = acc[rr][0]; v.y = acc[rr][1]; v.z = acc[rr][2]; v.w = acc[rr][3];
        *(float4*)&LU[(size_t)(r0 + 4 * trow + rr) * NMAT + jc0 + 4 * tcol] = v;
    }
}

// ---------------- mode-1 blocked solve: W += U^{-1} L^{-1} B  (R11-proven) ----------------
__global__ void __launch_bounds__(64) k_solve1(const float* __restrict__ LUT,
                                               const float* __restrict__ dinv,
                                               const float* __restrict__ B,
                                               float* __restrict__ W) {
    const int c = blockIdx.x;
    const int lane = threadIdx.x;
    float y[8];
    float Dc[64];
#pragma unroll
    for (int s = 0; s < 8; ++s) y[s] = B[(s * 64 + lane) * MRHS + c];
#pragma unroll
    for (int js = 0; js < 8; ++js) {
        const int base = js * 64;
        float a0 = 0.f, a1 = 0.f;
        for (int s = 0; s < js; ++s) {
#pragma unroll 8
            for (int m = 0; m < 64; m += 2) {
                a0 += LUT[(size_t)(s * 64 + m)     * NMAT + base + lane] * rdlane(y[s], m);
                a1 += LUT[(size_t)(s * 64 + m + 1) * NMAT + base + lane] * rdlane(y[s], m + 1);
            }
        }
        y[js] -= (a0 + a1);
#pragma unroll
        for (int q = 0; q < 64; ++q)
            Dc[q] = LUT[(size_t)(base + q) * NMAT + base + lane];
#pragma unroll 4
        for (int jl = 0; jl < 63; ++jl) {
            float yj = __shfl(y[js], jl);
            if (lane > jl) y[js] -= Dc[jl] * yj;
        }
    }
#pragma unroll
    for (int js = 7; js >= 0; --js) {
        const int base = js * 64;
        float a0 = 0.f, a1 = 0.f;
        for (int s = js + 1; s < 8; ++s) {
#pragma unroll 8
            for (int m = 0; m < 64; m += 2) {
                a0 += LUT[(size_t)(s * 64 + m)     * NMAT + base + lane] * rdlane(y[s], m);
                a1 += LUT[(size_t)(s * 64 + m + 1) * NMAT + base + lane] * rdlane(y[s], m + 1);
            }
        }
        y[js] -= (a0 + a1);
#pragma unroll
        for (int q = 0; q < 64; ++q)
            Dc[q] = LUT[(size_t)(base + q) * NMAT + base + lane];
        float dvb = dinv[base + lane];
#pragma unroll 4
        for (int jl = 63; jl >= 0; --jl) {
            float xj = __shfl(y[js], jl) * rdlane(dvb, jl);
            float t = y[js] - Dc[jl] * xj;
            y[js] = (lane < jl) ? t : ((lane == jl) ? xj : y[js]);
        }
    }
#pragma unroll
    for (int s = 0; s < 8; ++s)
        W[(s * 64 + lane) * MRHS + c] += y[s];
}

// ---------------- residual R = I[:,500:512] - A @ W  (f64 accumulate) ----------------
__global__ void __launch_bounds__(64) k_resid(const float* __restrict__ A,
                                              const float* __restrict__ W,
                                              float* __restrict__ R) {
    const int row = blockIdx.x;
    const int lane = threadIdx.x;
    double acc[MRHS];
#pragma unroll
    for (int cc = 0; cc < MRHS; ++cc) acc[cc] = 0.0;
    for (int k = lane; k < NMAT; k += 64) {
        float a = A[(size_t)row * NMAT + k];
#pragma unroll
        for (int cc = 0; cc < MRHS; ++cc) acc[cc] += (double)a * (double)W[k * MRHS + cc];
    }
#pragma unroll
    for (int cc = 0; cc < MRHS; ++cc) {
        double v = acc[cc];
#pragma unroll
        for (int off = 32; off > 0; off >>= 1) v += __shfl_xor(v, off);
        if (lane == cc) R[row * MRHS + cc] = (float)(((row == 500 + cc) ? 1.0 : 0.0) - v);
    }
}

// ---------------- out[i][p] = sum_k W[i][k] * e[k][p] ----------------
__global__ void __launch_bounds__(256) k_out(const float* __restrict__ W,
                                             const float* __restrict__ x,
                                             float* __restrict__ out) {
    const int p4 = blockIdx.x * 256 + threadIdx.x;  // 0..1023
    const int i = blockIdx.y;
    const float4* __restrict__ x4 = (const float4*)x;
    float ax = 0.f, ay = 0.f, az = 0.f, aw = 0.f;
#pragma unroll
    for (int k = 0; k < MRHS; ++k) {
        float w = W[i * MRHS + k];
        float4 v = x4[k * 1024 + p4];
        ax += w * v.x; ay += w * v.y; az += w * v.z; aw += w * v.w;
    }
    float4 o; o.x = ax; o.y = ay; o.z = az; o.w = aw;
    ((float4*)out)[(size_t)i * 1024 + p4] = o;
}

extern "C" void kernel_launch(void* const* d_in, const int* in_sizes, int n_in,
                              void* d_out, int out_size, void* d_ws, size_t ws_size,
                              hipStream_t stream) {
    (void)in_sizes; (void)n_in; (void)out_size; (void)ws_size;
    const float* M     = (const float*)d_in[0];
    const float* r     = (const float*)d_in[1];
    const float* cpart = (const float*)d_in[2];
    const float* x     = (const float*)d_in[3];
    float* out = (float*)d_out;
    float* ws  = (float*)d_ws;

    float* LU   = ws;                 // 262144
    float* A    = ws + 262144;        // 262144
    float* LUT  = ws + 524288;        // 262144
    float* W    = ws + 786432;        // 6144
    float* R    = ws + 792576;        // 6144
    float* dinv = ws + 798720;        // 512

    // 11-node chain
    k_setup<<<dim3(512), 256, 0, stream>>>(M, r, cpart, A, LU);

    k_panel128<512><<<dim3(1), 512, 0, stream>>>(LU, LUT, dinv, W, 0);
    k_update128<<<dim3(6, 7), 256, 0, stream>>>(LU, LUT, 0);
    k_panel128<384><<<dim3(1), 512, 0, stream>>>(LU, LUT, dinv, W, 128);
    k_update128<<<dim3(4, 5), 256, 0, stream>>>(LU, LUT, 128);
    k_panel128<256><<<dim3(1), 512, 0, stream>>>(LU, LUT, dinv, W, 256);
    k_update128<<<dim3(2, 3), 256, 0, stream>>>(LU, LUT, 256);
    k_panel128<128><<<dim3(1), 512, 0, stream>>>(LU, LUT, dinv, W, 384);  // + solve0

    // 1 iterative-refinement step (f64 residual)
    k_resid<<<dim3(NMAT), 64, 0, stream>>>(A, W, R);
    k_solve1<<<dim3(MRHS), 64, 0, stream>>>(LUT, dinv, R, W);

    k_out<<<dim3(4, 512), 256, 0, stream>>>(W, x, out);
}

// Round 20
// 2742.018 us; speedup vs baseline: 1.0002x; 1.0002x over previous
//
#include <hip/hip_runtime.h>
#include <cstddef>

#define NMAT 512
#define MRHS 12

__device__ __forceinline__ float rdlane(float v, int l) {
    return __int_as_float(__builtin_amdgcn_readlane(__float_as_int(v), l));
}

// ---------------- Stage 1: A = LU = constant_part + sum_e r[e] * M[e] ----------------
__global__ void __launch_bounds__(256) k_setup(const float* __restrict__ M,
                                               const float* __restrict__ r,
                                               const float* __restrict__ cpart,
                                               float* __restrict__ A,
                                               float* __restrict__ LU) {
    __shared__ float rs[1024];
    const int tid = threadIdx.x;
    for (int i = tid; i < 1024; i += 256) rs[i] = r[i];
    __syncthreads();
    const int idx2 = blockIdx.x * 256 + tid;          // 0..131071
    const float2* __restrict__ M2 = (const float2*)M;
    float2 a = ((const float2*)cpart)[idx2];
    float ax = a.x, ay = a.y;
#pragma unroll 16
    for (int e = 0; e < 1024; ++e) {
        float2 v = M2[(size_t)e * 131072u + idx2];
        float rv = rs[e];
        ax += rv * v.x; ay += rv * v.y;
    }
    float2 o; o.x = ax; o.y = ay;
    ((float2*)A)[idx2] = o;
    ((float2*)LU)[idx2] = o;
}

// ---------------- mode-0 solve (b = e_{500+c}), blocked, R11/R14-proven ----------------
__device__ __forceinline__ void solve0_f(const float* __restrict__ LUT,
                                         const float* __restrict__ dinv,
                                         float* __restrict__ W, int c, int lane) {
    float y[8];
#pragma unroll
    for (int s = 0; s < 8; ++s) y[s] = 0.f;
    y[7] = (lane == 52 + c) ? 1.0f : 0.0f;
    float Dc[64];
#pragma unroll
    for (int q = 0; q < 64; ++q)
        Dc[q] = LUT[(size_t)(448 + q) * NMAT + 448 + lane];
#pragma unroll 4
    for (int jl = 52; jl < 63; ++jl) {
        float yj = __shfl(y[7], jl);
        if (lane > jl) y[7] -= Dc[jl] * yj;
    }
#pragma unroll
    for (int js = 7; js >= 0; --js) {
        const int base = js * 64;
        float a0 = 0.f, a1 = 0.f;
        for (int s = js + 1; s < 8; ++s) {
#pragma unroll 8
            for (int m = 0; m < 64; m += 2) {
                a0 += LUT[(size_t)(s * 64 + m)     * NMAT + base + lane] * rdlane(y[s], m);
                a1 += LUT[(size_t)(s * 64 + m + 1) * NMAT + base + lane] * rdlane(y[s], m + 1);
            }
        }
        y[js] -= (a0 + a1);
#pragma unroll
        for (int q = 0; q < 64; ++q)
            Dc[q] = LUT[(size_t)(base + q) * NMAT + base + lane];
        float dvb = dinv[base + lane];
#pragma unroll 4
        for (int jl = 63; jl >= 0; --jl) {
            float xj = __shfl(y[js], jl) * rdlane(dvb, jl);
            float t = y[js] - Dc[jl] * xj;
            y[js] = (lane < jl) ? t : ((lane == jl) ? xj : y[js]);
        }
    }
#pragma unroll
    for (int s = 0; s < 8; ++s)
        W[(s * 64 + lane) * MRHS + c] = y[s];
}

// ---------------- NB=128 panel: factor 512x128 panel in ONE dispatch (R14-proven) --------
// launch_bounds(512, 1): one workgroup/CU -> 8 waves over 4 SIMDs = 2 waves/SIMD ->
// 256-VGPR budget; the ~170-reg live set (cA[64]+cB[64]+dA[16]+dB[16]) stays in regs.
template <int NR>
__global__ void __launch_bounds__(512, 1) k_panel128(const float* __restrict__ LU,
                                                     float* __restrict__ LUT,
                                                     float* __restrict__ dinvG,
                                                     float* __restrict__ W,
                                                     int k0) {
    constexpr int NG = (NR - 128) / 64;      // L21 row-groups (6,4,2,0)
    __shared__ float pivA[2][64], pivB[2][64];
    __shared__ float U11A[64 * 65];
    __shared__ float U11B[64 * 65];
    __shared__ float U12l[64 * 65];
    __shared__ float L10l[64 * 65];
    __shared__ float dinvL[128];
    const int tid = threadIdx.x, w = tid >> 6, lane = tid & 63;
    const int k1p = k0 + 128;

    // early-issue L21 rows (latency hidden under diag factor)
    float cA[64], cB[64];
    if (NG > 0 && w < NG) {
        const int row = k1p + w * 64 + lane;
#pragma unroll
        for (int c = 0; c < 64; ++c) cA[c] = LU[(size_t)row * NMAT + k0 + c];
#pragma unroll
        for (int c = 0; c < 64; ++c) cB[c] = LU[(size_t)row * NMAT + k0 + 64 + c];
    }
    float dA[16], dB[16];
#pragma unroll
    for (int s = 0; s < 16; ++s) {
        const int row = k0 + s * 8 + w;
        dA[s] = LU[(size_t)row * NMAT + k0 + lane];
        dB[s] = LU[(size_t)row * NMAT + k0 + 64 + lane];
    }
    // ---- left 64 pivots (cols k0..k0+63), rows 0..127 ----
    for (int j = 0; j < 64; ++j) {
        if (w == (j & 7)) {
#pragma unroll
            for (int s = 0; s < 16; ++s)
                if ((j >> 3) == s) {
                    pivA[j & 1][lane] = dA[s];
                    pivB[j & 1][lane] = dB[s];
                    U11A[j * 65 + lane] = dA[s];
                }
        }
        __syncthreads();
        float pvlA = pivA[j & 1][lane], pvlB = pivB[j & 1][lane];
        float pinv = 1.0f / __shfl(pvlA, j);
        if (tid == 0) dinvL[j] = pinv;
#pragma unroll
        for (int s = 0; s < 16; ++s) {
            int i = s * 8 + w;
            if (i > j) {                                  // wave-uniform
                float l = __shfl(dA[s], j) * pinv;
                float updA = dA[s] - l * pvlA;
                dA[s] = (lane > j) ? updA : ((lane == j) ? l : dA[s]);
                dB[s] -= l * pvlB;                        // all 64 right-half cols
            }
        }
    }
    __syncthreads();
    // publish U12 (rows 0..63 of right half) and L10 (rows 64..127 of left half)
#pragma unroll
    for (int s = 0; s < 8; ++s) {
        int i = s * 8 + w;                                // 0..63
        U12l[i * 65 + lane] = dB[s];
        L10l[i * 65 + lane] = dA[s + 8];                  // row 64+i, left half
    }
    __syncthreads();
    // ---- L21 left substitution + Schur on right half ----
    if (NG > 0 && w < NG) {
#pragma unroll
        for (int j = 0; j < 64; ++j) {
            float lj = cA[j] * dinvL[j];
            cA[j] = lj;
            float rowv = U11A[j * 65 + lane];
#pragma unroll
            for (int jj = j + 1; jj < 64; ++jj)
                cA[jj] -= lj * rdlane(rowv, jj);
        }
#pragma unroll
        for (int j = 0; j < 64; ++j) {
            float lj = cA[j];
            float rowv = U12l[j * 65 + lane];
#pragma unroll
            for (int c = 0; c < 64; ++c)
                cB[c] -= lj * rdlane(rowv, c);
        }
    }
    // ---- right 64 pivots (cols k0+64..k0+127), rows 64..127 ----
    for (int j = 64; j < 128; ++j) {
        const int jj = j - 64;
        if (w == (j & 7)) {
#pragma unroll
            for (int s = 8; s < 16; ++s)
                if ((j >> 3) == s) {
                    pivB[j & 1][lane] = dB[s];
                    U11B[jj * 65 + lane] = dB[s];
                }
        }
        __syncthreads();
        float pvlB = pivB[j & 1][lane];
        float pinv = 1.0f / __shfl(pvlB, jj);
        if (tid == 0) dinvL[j] = pinv;
#pragma unroll
        for (int s = 8; s < 16; ++s) {
            int i = s * 8 + w;
            if (i > j) {
                float l = __shfl(dB[s], jj) * pinv;
                float updB = dB[s] - l * pvlB;
                dB[s] = (lane > jj) ? updB : ((lane == jj) ? l : dB[s]);
            }
        }
    }
    __syncthreads();
    // ---- L21 right substitution ----
    if (NG > 0 && w < NG) {
#pragma unroll
        for (int jj = 0; jj < 64; ++jj) {
            float lj = cB[jj] * dinvL[64 + jj];
            cB[jj] = lj;
            float rowv = U11B[jj * 65 + lane];
#pragma unroll
            for (int c = jj + 1; c < 64; ++c)
                cB[c] -= lj * rdlane(rowv, c);
        }
    }
    // ---- writes ----
    if (tid < 128) dinvG[k0 + tid] = dinvL[tid];
#pragma unroll
    for (int q = 0; q < 16; ++q) {
        const int c = w * 16 + q;                        // 0..127
        float v0, v1;
        if (c < 64) { v0 = U11A[lane * 65 + c];        v1 = L10l[lane * 65 + c]; }
        else        { v0 = U12l[lane * 65 + (c - 64)]; v1 = U11B[lane * 65 + (c - 64)]; }
        LUT[(size_t)(k0 + c) * NMAT + k0 + lane]      = v0;   // rows 0..63
        LUT[(size_t)(k0 + c) * NMAT + k0 + 64 + lane] = v1;   // rows 64..127
    }
    if (NG > 0 && w < NG) {
        const int row = k1p + w * 64 + lane;
#pragma unroll
        for (int c = 0; c < 64; ++c)
            LUT[(size_t)(k0 + c) * NMAT + row] = cA[c];
#pragma unroll
        for (int c = 0; c < 64; ++c)
            LUT[(size_t)(k0 + 64 + c) * NMAT + row] = cB[c];
    }
    if (NR == 128) {
        // final panel: LUT complete -> fused mode-0 solves (R14-proven fusion)
        __threadfence_block();
        __syncthreads();
        for (int c = w; c < MRHS; c += 8)
            solve0_f(LUT, dinvG, W, c, lane);
    }
}

// ---------------- NB=128 update: trsm (wave 0) + U12^T or K=128 gemm (R14-proven) --------
// launch_bounds(256, 1): wave-0's y[128] stays in regs (512-VGPR budget).
__global__ void __launch_bounds__(256, 1) k_update128(float* __restrict__ LU,
                                                      float* __restrict__ LUT,
                                                      int k0) {
    __shared__ float yLDS[128 * 65];
    __shared__ float sL21[64 * 132];
    const int k1p = k0 + 128;
    const int jc0 = k1p + blockIdx.x * 64;
    const int tid = threadIdx.x, w = tid >> 6, lane = tid & 63;
    const bool urole = (blockIdx.y > 0);
    const int r0 = k1p + ((int)blockIdx.y - 1) * 64;

    float acc[4][4];
    const int trow = tid >> 4, tcol = tid & 15;
    if (urole) {
#pragma unroll
        for (int rr = 0; rr < 4; ++rr) {
            float4 v = *(const float4*)&LU[(size_t)(r0 + 4 * trow + rr) * NMAT + jc0 + 4 * tcol];
            acc[rr][0] = v.x; acc[rr][1] = v.y; acc[rr][2] = v.z; acc[rr][3] = v.w;
        }
        if (w > 0) {   // waves 1..3 stage L21 while wave 0 runs the trsm
            for (int idx = tid - 64; idx < 8192; idx += 192) {
                int kk = idx >> 6, row = idx & 63;
                sL21[row * 132 + kk] = LUT[(size_t)(k0 + kk) * NMAT + r0 + row];
            }
        }
    }
    if (w == 0) {
        // forward substitution, lane = column, y[i] = row i of this column tile
        float y[128];
#pragma unroll
        for (int i = 0; i < 128; ++i)
            y[i] = LU[(size_t)(k0 + i) * NMAT + jc0 + lane];
#pragma unroll
        for (int tc = 0; tc < 8; ++tc) {
            float cvLo[16], cvHi[16];
#pragma unroll
            for (int q = 0; q < 16; ++q) {
                cvLo[q] = LUT[(size_t)(k0 + tc * 16 + q) * NMAT + k0 + lane];
                cvHi[q] = LUT[(size_t)(k0 + tc * 16 + q) * NMAT + k0 + 64 + lane];
            }
#pragma unroll
            for (int q = 0; q < 16; ++q) {
                const int t = tc * 16 + q;
                float yt = y[t];
#pragma unroll
                for (int i = t + 1; i < 128; ++i) {
                    float lij = (i < 64) ? rdlane(cvLo[q], i) : rdlane(cvHi[q], i - 64);
                    y[i] -= lij * yt;
                }
            }
        }
#pragma unroll
        for (int i = 0; i < 128; ++i) yLDS[i * 65 + lane] = y[i];
    }
    __syncthreads();
    if (!urole) {
        for (int idx = tid; idx < 8192; idx += 256) {
            int jc = idx >> 7, i = idx & 127;
            LUT[(size_t)(jc0 + jc) * NMAT + k0 + i] = yLDS[i * 65 + jc];
        }
        return;
    }
#pragma unroll 4
    for (int kk = 0; kk < 128; ++kk) {
        float b0 = yLDS[kk * 65 + 4 * tcol + 0];
        float b1 = yLDS[kk * 65 + 4 * tcol + 1];
        float b2 = yLDS[kk * 65 + 4 * tcol + 2];
        float b3 = yLDS[kk * 65 + 4 * tcol + 3];
#pragma unroll
        for (int rr = 0; rr < 4; ++rr) {
            float a = sL21[(4 * trow + rr) * 132 + kk];
            acc[rr][0] -= a * b0; acc[rr][1] -= a * b1;
            acc[rr][2] -= a * b2; acc[rr][3] -= a * b3;
        }
    }
#pragma unroll
    for (int rr = 0; rr < 4; ++rr) {
        float4 v; v.x = acc[rr][0]; v.y = acc[rr][1]; v.z = acc[rr][2]; v.w = acc[rr][3];
        *(float4*)&LU[(size_t)(r0 + 4 * trow + rr) * NMAT + jc0 + 4 * tcol] = v;
    }
}

// ---------------- mode-1 blocked solve: W += U^{-1} L^{-1} B  (R11-proven) ----------------
__global__ void __launch_bounds__(64) k_solve1(const float* __restrict__ LUT,
                                               const float* __restrict__ dinv,
                                               const float* __restrict__ B,
                                               float* __restrict__ W) {
    const int c = blockIdx.x;
    const int lane = threadIdx.x;
    float y[8];
    float Dc[64];
#pragma unroll
    for (int s = 0; s < 8; ++s) y[s] = B[(s * 64 + lane) * MRHS + c];
#pragma unroll
    for (int js = 0; js < 8; ++js) {
        const int base = js * 64;
        float a0 = 0.f, a1 = 0.f;
        for (int s = 0; s < js; ++s) {
#pragma unroll 8
            for (int m = 0; m < 64; m += 2) {
                a0 += LUT[(size_t)(s * 64 + m)     * NMAT + base + lane] * rdlane(y[s], m);
                a1 += LUT[(size_t)(s * 64 + m + 1) * NMAT + base + lane] * rdlane(y[s], m + 1);
            }
        }
        y[js] -= (a0 + a1);
#pragma unroll
        for (int q = 0; q < 64; ++q)
            Dc[q] = LUT[(size_t)(base + q) * NMAT + base + lane];
#pragma unroll 4
        for (int jl = 0; jl < 63; ++jl) {
            float yj = __shfl(y[js], jl);
            if (lane > jl) y[js] -= Dc[jl] * yj;
        }
    }
#pragma unroll
    for (int js = 7; js >= 0; --js) {
        const int base = js * 64;
        float a0 = 0.f, a1 = 0.f;
        for (int s = js + 1; s < 8; ++s) {
#pragma unroll 8
            for (int m = 0; m < 64; m += 2) {
                a0 += LUT[(size_t)(s * 64 + m)     * NMAT + base + lane] * rdlane(y[s], m);
                a1 += LUT[(size_t)(s * 64 + m + 1) * NMAT + base + lane] * rdlane(y[s], m + 1);
            }
        }
        y[js] -= (a0 + a1);
#pragma unroll
        for (int q = 0; q < 64; ++q)
            Dc[q] = LUT[(size_t)(base + q) * NMAT + base + lane];
        float dvb = dinv[base + lane];
#pragma unroll 4
        for (int jl = 63; jl >= 0; --jl) {
            float xj = __shfl(y[js], jl) * rdlane(dvb, jl);
            float t = y[js] - Dc[jl] * xj;
            y[js] = (lane < jl) ? t : ((lane == jl) ? xj : y[js]);
        }
    }
#pragma unroll
    for (int s = 0; s < 8; ++s)
        W[(s * 64 + lane) * MRHS + c] += y[s];
}

// ---------------- residual R = I[:,500:512] - A @ W  (f64 accumulate) ----------------
__global__ void __launch_bounds__(64) k_resid(const float* __restrict__ A,
                                              const float* __restrict__ W,
                                              float* __restrict__ R) {
    const int row = blockIdx.x;
    const int lane = threadIdx.x;
    double acc[MRHS];
#pragma unroll
    for (int cc = 0; cc < MRHS; ++cc) acc[cc] = 0.0;
    for (int k = lane; k < NMAT; k += 64) {
        float a = A[(size_t)row * NMAT + k];
#pragma unroll
        for (int cc = 0; cc < MRHS; ++cc) acc[cc] += (double)a * (double)W[k * MRHS + cc];
    }
#pragma unroll
    for (int cc = 0; cc < MRHS; ++cc) {
        double v = acc[cc];
#pragma unroll
        for (int off = 32; off > 0; off >>= 1) v += __shfl_xor(v, off);
        if (lane == cc) R[row * MRHS + cc] = (float)(((row == 500 + cc) ? 1.0 : 0.0) - v);
    }
}

// ---------------- out[i][p] = sum_k W[i][k] * e[k][p] ----------------
__global__ void __launch_bounds__(256) k_out(const float* __restrict__ W,
                                             const float* __restrict__ x,
                                             float* __restrict__ out) {
    const int p4 = blockIdx.x * 256 + threadIdx.x;  // 0..1023
    const int i = blockIdx.y;
    const float4* __restrict__ x4 = (const float4*)x;
    float ax = 0.f, ay = 0.f, az = 0.f, aw = 0.f;
#pragma unroll
    for (int k = 0; k < MRHS; ++k) {
        float w = W[i * MRHS + k];
        float4 v = x4[k * 1024 + p4];
        ax += w * v.x; ay += w * v.y; az += w * v.z; aw += w * v.w;
    }
    float4 o; o.x = ax; o.y = ay; o.z = az; o.w = aw;
    ((float4*)out)[(size_t)i * 1024 + p4] = o;
}

extern "C" void kernel_launch(void* const* d_in, const int* in_sizes, int n_in,
                              void* d_out, int out_size, void* d_ws, size_t ws_size,
                              hipStream_t stream) {
    (void)in_sizes; (void)n_in; (void)out_size; (void)ws_size;
    const float* M     = (const float*)d_in[0];
    const float* r     = (const float*)d_in[1];
    const float* cpart = (const float*)d_in[2];
    const float* x     = (const float*)d_in[3];
    float* out = (float*)d_out;
    float* ws  = (float*)d_ws;

    float* LU   = ws;                 // 262144
    float* A    = ws + 262144;        // 262144
    float* LUT  = ws + 524288;        // 262144
    float* W    = ws + 786432;        // 6144
    float* R    = ws + 792576;        // 6144
    float* dinv = ws + 798720;        // 512

    // 11-node chain
    k_setup<<<dim3(512), 256, 0, stream>>>(M, r, cpart, A, LU);

    k_panel128<512><<<dim3(1), 512, 0, stream>>>(LU, LUT, dinv, W, 0);
    k_update128<<<dim3(6, 7), 256, 0, stream>>>(LU, LUT, 0);
    k_panel128<384><<<dim3(1), 512, 0, stream>>>(LU, LUT, dinv, W, 128);
    k_update128<<<dim3(4, 5), 256, 0, stream>>>(LU, LUT, 128);
    k_panel128<256><<<dim3(1), 512, 0, stream>>>(LU, LUT, dinv, W, 256);
    k_update128<<<dim3(2, 3), 256, 0, stream>>>(LU, LUT, 256);
    k_panel128<128><<<dim3(1), 512, 0, stream>>>(LU, LUT, dinv, W, 384);  // + solve0

    // 1 iterative-refinement step (f64 residual)
    k_resid<<<dim3(NMAT), 64, 0, stream>>>(A, W, R);
    k_solve1<<<dim3(MRHS), 64, 0, stream>>>(LUT, dinv, R, W);

    k_out<<<dim3(4, 512), 256, 0, stream>>>(W, x, out);
}

// Round 21
// 1458.364 us; speedup vs baseline: 1.8806x; 1.8802x over previous
//
#include <hip/hip_runtime.h>
#include <cstddef>

#define NMAT 512
#define MRHS 12

__device__ __forceinline__ float rdlane(float v, int l) {
    return __int_as_float(__builtin_amdgcn_readlane(__float_as_int(v), l));
}

// ---------------- Stage 1: A = LU = constant_part + sum_e r[e] * M[e] ----------------
__global__ void __launch_bounds__(256) k_setup(const float* __restrict__ M,
                                               const float* __restrict__ r,
                                               const float* __restrict__ cpart,
                                               float* __restrict__ A,
                                               float* __restrict__ LU) {
    __shared__ float rs[1024];
    const int tid = threadIdx.x;
    for (int i = tid; i < 1024; i += 256) rs[i] = r[i];
    __syncthreads();
    const int idx2 = blockIdx.x * 256 + tid;          // 0..131071
    const float2* __restrict__ M2 = (const float2*)M;
    float2 a = ((const float2*)cpart)[idx2];
    float ax = a.x, ay = a.y;
#pragma unroll 16
    for (int e = 0; e < 1024; ++e) {
        float2 v = M2[(size_t)e * 131072u + idx2];
        float rv = rs[e];
        ax += rv * v.x; ay += rv * v.y;
    }
    float2 o; o.x = ax; o.y = ay;
    ((float2*)A)[idx2] = o;
    ((float2*)LU)[idx2] = o;
}

// ---------------- NB=128 panel, spill-free: two-pass L21 ----------------
// 512 thr = 8 waves, VGPR cap 128. Peak live: diag phase cA[64]+dA[16]+dB[16] ~= 96.
// Pass A: left substitution on cA -> LUT (cA dies). Right pivots (dB only).
// Pass B: load cB, Schur with cA reloaded coalesced from LUT (8-reg chunks), right subst.
// Identical FP ops/order to the R14/R19-passed version.
template <int NR>
__global__ void __launch_bounds__(512) k_panel128(const float* __restrict__ LU,
                                                  float* __restrict__ LUT,
                                                  float* __restrict__ dinvG,
                                                  int k0) {
    constexpr int NG = (NR - 128) / 64;      // L21 row-groups (6,4,2,0)
    __shared__ float pivA[2][64], pivB[2][64];
    __shared__ float U11A[64 * 65];
    __shared__ float U11B[64 * 65];
    __shared__ float U12l[64 * 65];
    __shared__ float L10l[64 * 65];
    __shared__ float dinvL[128];
    const int tid = threadIdx.x, w = tid >> 6, lane = tid & 63;
    const int k1p = k0 + 128;

    // early-issue LEFT half of L21 rows only (latency hidden under diag factor)
    float cA[64];
    if (NG > 0 && w < NG) {
        const int row = k1p + w * 64 + lane;
#pragma unroll
        for (int c = 0; c < 64; ++c) cA[c] = LU[(size_t)row * NMAT + k0 + c];
    }
    float dA[16], dB[16];
#pragma unroll
    for (int s = 0; s < 16; ++s) {
        const int row = k0 + s * 8 + w;
        dA[s] = LU[(size_t)row * NMAT + k0 + lane];
        dB[s] = LU[(size_t)row * NMAT + k0 + 64 + lane];
    }
    // ---- left 64 pivots (cols k0..k0+63), rows 0..127 ----
    for (int j = 0; j < 64; ++j) {
        if (w == (j & 7)) {
#pragma unroll
            for (int s = 0; s < 16; ++s)
                if ((j >> 3) == s) {
                    pivA[j & 1][lane] = dA[s];
                    pivB[j & 1][lane] = dB[s];
                    U11A[j * 65 + lane] = dA[s];
                }
        }
        __syncthreads();
        float pvlA = pivA[j & 1][lane], pvlB = pivB[j & 1][lane];
        float pinv = 1.0f / __shfl(pvlA, j);
        if (tid == 0) dinvL[j] = pinv;
#pragma unroll
        for (int s = 0; s < 16; ++s) {
            int i = s * 8 + w;
            if (i > j) {                                  // wave-uniform
                float l = __shfl(dA[s], j) * pinv;
                float updA = dA[s] - l * pvlA;
                dA[s] = (lane > j) ? updA : ((lane == j) ? l : dA[s]);
                dB[s] -= l * pvlB;                        // all 64 right-half cols
            }
        }
    }
    __syncthreads();
    // publish U12 (rows 0..63 of right half) and L10 (rows 64..127 of left half)
#pragma unroll
    for (int s = 0; s < 8; ++s) {
        int i = s * 8 + w;                                // 0..63
        U12l[i * 65 + lane] = dB[s];
        L10l[i * 65 + lane] = dA[s + 8];                  // row 64+i, left half
    }
    __syncthreads();
    // ---- pass A: L21 left substitution; write to LUT; cA dies ----
    if (NG > 0 && w < NG) {
        const int row = k1p + w * 64 + lane;
#pragma unroll
        for (int j = 0; j < 64; ++j) {
            float lj = cA[j] * dinvL[j];
            cA[j] = lj;
            float rowv = U11A[j * 65 + lane];
#pragma unroll
            for (int jj = j + 1; jj < 64; ++jj)
                cA[jj] -= lj * rdlane(rowv, jj);
        }
#pragma unroll
        for (int c = 0; c < 64; ++c)
            LUT[(size_t)(k0 + c) * NMAT + row] = cA[c];
    }
    // ---- right 64 pivots (cols k0+64..k0+127), rows 64..127 (dB only) ----
    for (int j = 64; j < 128; ++j) {
        const int jj = j - 64;
        if (w == (j & 7)) {
#pragma unroll
            for (int s = 8; s < 16; ++s)
                if ((j >> 3) == s) {
                    pivB[j & 1][lane] = dB[s];
                    U11B[jj * 65 + lane] = dB[s];
                }
        }
        __syncthreads();
        float pvlB = pivB[j & 1][lane];
        float pinv = 1.0f / __shfl(pvlB, jj);
        if (tid == 0) dinvL[j] = pinv;
#pragma unroll
        for (int s = 8; s < 16; ++s) {
            int i = s * 8 + w;
            if (i > j) {
                float l = __shfl(dB[s], jj) * pinv;
                float updB = dB[s] - l * pvlB;
                dB[s] = (lane > jj) ? updB : ((lane == jj) ? l : dB[s]);
            }
        }
    }
    __syncthreads();
    // ---- pass B: load cB; Schur with cA reloaded from LUT; right substitution ----
    if (NG > 0 && w < NG) {
        const int row = k1p + w * 64 + lane;
        float cB[64];
#pragma unroll
        for (int c = 0; c < 64; ++c) cB[c] = LU[(size_t)row * NMAT + k0 + 64 + c];
#pragma unroll
        for (int jc = 0; jc < 8; ++jc) {
            float av[8];
#pragma unroll
            for (int q = 0; q < 8; ++q)
                av[q] = LUT[(size_t)(k0 + jc * 8 + q) * NMAT + row];   // coalesced cA reload
#pragma unroll
            for (int q = 0; q < 8; ++q) {
                const int j = jc * 8 + q;
                float rowv = U12l[j * 65 + lane];
#pragma unroll
                for (int c = 0; c < 64; ++c)
                    cB[c] -= av[q] * rdlane(rowv, c);
            }
        }
#pragma unroll
        for (int jj = 0; jj < 64; ++jj) {
            float lj = cB[jj] * dinvL[64 + jj];
            cB[jj] = lj;
            float rowv = U11B[jj * 65 + lane];
#pragma unroll
            for (int c = jj + 1; c < 64; ++c)
                cB[c] -= lj * rdlane(rowv, c);
        }
#pragma unroll
        for (int c = 0; c < 64; ++c)
            LUT[(size_t)(k0 + 64 + c) * NMAT + row] = cB[c];
    }
    // ---- writes: dinv + transposed diag block ----
    if (tid < 128) dinvG[k0 + tid] = dinvL[tid];
#pragma unroll
    for (int q = 0; q < 16; ++q) {
        const int c = w * 16 + q;                        // 0..127
        float v0, v1;
        if (c < 64) { v0 = U11A[lane * 65 + c];        v1 = L10l[lane * 65 + c]; }
        else        { v0 = U12l[lane * 65 + (c - 64)]; v1 = U11B[lane * 65 + (c - 64)]; }
        LUT[(size_t)(k0 + c) * NMAT + k0 + lane]      = v0;   // rows 0..63
        LUT[(size_t)(k0 + c) * NMAT + k0 + 64 + lane] = v1;   // rows 64..127
    }
}

// ---------------- NB=128 update, spill-free: trsm split across waves 0/1 ----------------
// Wave 0: rows 0..63 (y[64]) -> yLDS. Wave 1: rows 64..127 (y[64]): correction from
// yLDS + right-half substitution. Waves 2..3 stage sL21 concurrently. Peak live ~90.
__global__ void __launch_bounds__(256) k_update128(float* __restrict__ LU,
                                                   float* __restrict__ LUT,
                                                   int k0) {
    __shared__ float yLDS[128 * 65];
    __shared__ float sL21[64 * 132];
    const int k1p = k0 + 128;
    const int jc0 = k1p + blockIdx.x * 64;
    const int tid = threadIdx.x, w = tid >> 6, lane = tid & 63;
    const bool urole = (blockIdx.y > 0);
    const int r0 = k1p + ((int)blockIdx.y - 1) * 64;

    float acc[4][4];
    const int trow = tid >> 4, tcol = tid & 15;
    if (urole) {
#pragma unroll
        for (int rr = 0; rr < 4; ++rr) {
            float4 v = *(const float4*)&LU[(size_t)(r0 + 4 * trow + rr) * NMAT + jc0 + 4 * tcol];
            acc[rr][0] = v.x; acc[rr][1] = v.y; acc[rr][2] = v.z; acc[rr][3] = v.w;
        }
        if (w >= 2) {   // waves 2..3 stage L21 while waves 0..1 run the trsm
            for (int idx = tid - 128; idx < 8192; idx += 128) {
                int kk = idx >> 6, row = idx & 63;
                sL21[row * 132 + kk] = LUT[(size_t)(k0 + kk) * NMAT + r0 + row];
            }
        }
    }
    float y[64];
    if (w == 0) {
        // rows 0..63: forward substitution with cols 0..63
#pragma unroll
        for (int i = 0; i < 64; ++i)
            y[i] = LU[(size_t)(k0 + i) * NMAT + jc0 + lane];
#pragma unroll
        for (int tc = 0; tc < 4; ++tc) {
            float cv[16];
#pragma unroll
            for (int q = 0; q < 16; ++q)
                cv[q] = LUT[(size_t)(k0 + tc * 16 + q) * NMAT + k0 + lane];
#pragma unroll
            for (int q = 0; q < 16; ++q) {
                const int t = tc * 16 + q;
                float yt = y[t];
#pragma unroll
                for (int i = t + 1; i < 64; ++i)
                    y[i] -= rdlane(cv[q], i) * yt;
            }
        }
#pragma unroll
        for (int i = 0; i < 64; ++i) yLDS[i * 65 + lane] = y[i];
    } else if (w == 1) {
        // rows 64..127: load now; correct after barrier
#pragma unroll
        for (int i = 0; i < 64; ++i)
            y[i] = LU[(size_t)(k0 + 64 + i) * NMAT + jc0 + lane];
    }
    __syncthreads();
    if (w == 1) {
        // correction: y[i] -= sum_t L[64+i][t] * yLo[t]
#pragma unroll
        for (int tc = 0; tc < 4; ++tc) {
            float cvH[16];
#pragma unroll
            for (int q = 0; q < 16; ++q)
                cvH[q] = LUT[(size_t)(k0 + tc * 16 + q) * NMAT + k0 + 64 + lane];
#pragma unroll
            for (int q = 0; q < 16; ++q) {
                const int t = tc * 16 + q;
                float yt = yLDS[t * 65 + lane];
#pragma unroll
                for (int i = 0; i < 64; ++i)
                    y[i] -= rdlane(cvH[q], i) * yt;
            }
        }
        // right-half substitution (cols 64..127)
#pragma unroll
        for (int tc = 0; tc < 4; ++tc) {
            float cv2[16];
#pragma unroll
            for (int q = 0; q < 16; ++q)
                cv2[q] = LUT[(size_t)(k0 + 64 + tc * 16 + q) * NMAT + k0 + 64 + lane];
#pragma unroll
            for (int q = 0; q < 16; ++q) {
                const int t = tc * 16 + q;
                float yt = y[t];
#pragma unroll
                for (int i = t + 1; i < 64; ++i)
                    y[i] -= rdlane(cv2[q], i) * yt;
            }
        }
#pragma unroll
        for (int i = 0; i < 64; ++i) yLDS[(64 + i) * 65 + lane] = y[i];
    }
    __syncthreads();
    if (!urole) {
        for (int idx = tid; idx < 8192; idx += 256) {
            int jc = idx >> 7, i = idx & 127;
            LUT[(size_t)(jc0 + jc) * NMAT + k0 + i] = yLDS[i * 65 + jc];
        }
        return;
    }
#pragma unroll 4
    for (int kk = 0; kk < 128; ++kk) {
        float b0 = yLDS[kk * 65 + 4 * tcol + 0];
        float b1 = yLDS[kk * 65 + 4 * tcol + 1];
        float b2 = yLDS[kk * 65 + 4 * tcol + 2];
        float b3 = yLDS[kk * 65 + 4 * tcol + 3];
#pragma unroll
        for (int rr = 0; rr < 4; ++rr) {
            float a = sL21[(4 * trow + rr) * 132 + kk];
            acc[rr][0] -= a * b0; acc[rr][1] -= a * b1;
            acc[rr][2] -= a * b2; acc[rr][3] -= a * b3;
        }
    }
#pragma unroll
    for (int rr = 0; rr < 4; ++rr) {
        float4 v; v.x = acc[rr][0]; v.y = acc[rr][1]; v.z = acc[rr][2]; v.w = acc[rr][3];
        *(float4*)&LU[(size_t)(r0 + 4 * trow + rr) * NMAT + jc0 + 4 * tcol] = v;
    }
}

// ---------------- BLOCKED triangular solves (R11/R18-proven) ----------------
__global__ void __launch_bounds__(64) k_solve(const float* __restrict__ LUT,
                                              const float* __restrict__ dinv,
                                              const float* __restrict__ B,
                                              float* __restrict__ W, int mode) {
    const int c = blockIdx.x;
    const int lane = threadIdx.x;
    float y[8];
    float Dc[64];
    if (mode) {
#pragma unroll
        for (int s = 0; s < 8; ++s) y[s] = B[(s * 64 + lane) * MRHS + c];
#pragma unroll
        for (int js = 0; js < 8; ++js) {
            const int base = js * 64;
            float a0 = 0.f, a1 = 0.f;
            for (int s = 0; s < js; ++s) {
#pragma unroll 8
                for (int m = 0; m < 64; m += 2) {
                    a0 += LUT[(size_t)(s * 64 + m)     * NMAT + base + lane] * rdlane(y[s], m);
                    a1 += LUT[(size_t)(s * 64 + m + 1) * NMAT + base + lane] * rdlane(y[s], m + 1);
                }
            }
            y[js] -= (a0 + a1);
#pragma unroll
            for (int q = 0; q < 64; ++q)
                Dc[q] = LUT[(size_t)(base + q) * NMAT + base + lane];
#pragma unroll 4
            for (int jl = 0; jl < 63; ++jl) {
                float yj = __shfl(y[js], jl);
                if (lane > jl) y[js] -= Dc[jl] * yj;
            }
        }
    } else {
#pragma unroll
        for (int s = 0; s < 8; ++s) y[s] = 0.f;
        y[7] = (lane == 52 + c) ? 1.0f : 0.0f;
#pragma unroll
        for (int q = 0; q < 64; ++q)
            Dc[q] = LUT[(size_t)(448 + q) * NMAT + 448 + lane];
#pragma unroll 4
        for (int jl = 52; jl < 63; ++jl) {
            float yj = __shfl(y[7], jl);
            if (lane > jl) y[7] -= Dc[jl] * yj;
        }
    }
    // blocked backward: U x = y
#pragma unroll
    for (int js = 7; js >= 0; --js) {
        const int base = js * 64;
        float a0 = 0.f, a1 = 0.f;
        for (int s = js + 1; s < 8; ++s) {
#pragma unroll 8
            for (int m = 0; m < 64; m += 2) {
                a0 += LUT[(size_t)(s * 64 + m)     * NMAT + base + lane] * rdlane(y[s], m);
                a1 += LUT[(size_t)(s * 64 + m + 1) * NMAT + base + lane] * rdlane(y[s], m + 1);
            }
        }
        y[js] -= (a0 + a1);
#pragma unroll
        for (int q = 0; q < 64; ++q)
            Dc[q] = LUT[(size_t)(base + q) * NMAT + base + lane];
        float dvb = dinv[base + lane];
#pragma unroll 4
        for (int jl = 63; jl >= 0; --jl) {
            float xj = __shfl(y[js], jl) * rdlane(dvb, jl);
            float t = y[js] - Dc[jl] * xj;
            y[js] = (lane < jl) ? t : ((lane == jl) ? xj : y[js]);
        }
    }
#pragma unroll
    for (int s = 0; s < 8; ++s) {
        int row = s * 64 + lane;
        if (mode) W[row * MRHS + c] += y[s];
        else      W[row * MRHS + c] = y[s];
    }
}

// ---------------- residual R = I[:,500:512] - A @ W  (f64 accumulate) ----------------
__global__ void __launch_bounds__(64) k_resid(const float* __restrict__ A,
                                              const float* __restrict__ W,
                                              float* __restrict__ R) {
    const int row = blockIdx.x;
    const int lane = threadIdx.x;
    double acc[MRHS];
#pragma unroll
    for (int cc = 0; cc < MRHS; ++cc) acc[cc] = 0.0;
    for (int k = lane; k < NMAT; k += 64) {
        float a = A[(size_t)row * NMAT + k];
#pragma unroll
        for (int cc = 0; cc < MRHS; ++cc) acc[cc] += (double)a * (double)W[k * MRHS + cc];
    }
#pragma unroll
    for (int cc = 0; cc < MRHS; ++cc) {
        double v = acc[cc];
#pragma unroll
        for (int off = 32; off > 0; off >>= 1) v += __shfl_xor(v, off);
        if (lane == cc) R[row * MRHS + cc] = (float)(((row == 500 + cc) ? 1.0 : 0.0) - v);
    }
}

// ---------------- out[i][p] = sum_k W[i][k] * e[k][p] ----------------
__global__ void __launch_bounds__(256) k_out(const float* __restrict__ W,
                                             const float* __restrict__ x,
                                             float* __restrict__ out) {
    const int p4 = blockIdx.x * 256 + threadIdx.x;  // 0..1023
    const int i = blockIdx.y;
    const float4* __restrict__ x4 = (const float4*)x;
    float ax = 0.f, ay = 0.f, az = 0.f, aw = 0.f;
#pragma unroll
    for (int k = 0; k < MRHS; ++k) {
        float w = W[i * MRHS + k];
        float4 v = x4[k * 1024 + p4];
        ax += w * v.x; ay += w * v.y; az += w * v.z; aw += w * v.w;
    }
    float4 o; o.x = ax; o.y = ay; o.z = az; o.w = aw;
    ((float4*)out)[(size_t)i * 1024 + p4] = o;
}

extern "C" void kernel_launch(void* const* d_in, const int* in_sizes, int n_in,
                              void* d_out, int out_size, void* d_ws, size_t ws_size,
                              hipStream_t stream) {
    (void)in_sizes; (void)n_in; (void)out_size; (void)ws_size;
    const float* M     = (const float*)d_in[0];
    const float* r     = (const float*)d_in[1];
    const float* cpart = (const float*)d_in[2];
    const float* x     = (const float*)d_in[3];
    float* out = (float*)d_out;
    float* ws  = (float*)d_ws;

    float* LU   = ws;                 // 262144
    float* A    = ws + 262144;        // 262144
    float* LUT  = ws + 524288;        // 262144
    float* W    = ws + 786432;        // 6144
    float* R    = ws + 792576;        // 6144
    float* dinv = ws + 798720;        // 512

    // 12-node chain
    k_setup<<<dim3(512), 256, 0, stream>>>(M, r, cpart, A, LU);

    k_panel128<512><<<dim3(1), 512, 0, stream>>>(LU, LUT, dinv, 0);
    k_update128<<<dim3(6, 7), 256, 0, stream>>>(LU, LUT, 0);
    k_panel128<384><<<dim3(1), 512, 0, stream>>>(LU, LUT, dinv, 128);
    k_update128<<<dim3(4, 5), 256, 0, stream>>>(LU, LUT, 128);
    k_panel128<256><<<dim3(1), 512, 0, stream>>>(LU, LUT, dinv, 256);
    k_update128<<<dim3(2, 3), 256, 0, stream>>>(LU, LUT, 256);
    k_panel128<128><<<dim3(1), 512, 0, stream>>>(LU, LUT, dinv, 384);

    // W = A^{-1} I[:,500:512] + 1 iterative-refinement step
    k_solve<<<dim3(MRHS), 64, 0, stream>>>(LUT, dinv, R /*unused*/, W, 0);
    k_resid<<<dim3(NMAT), 64, 0, stream>>>(A, W, R);
    k_solve<<<dim3(MRHS), 64, 0, stream>>>(LUT, dinv, R, W, 1);

    k_out<<<dim3(4, 512), 256, 0, stream>>>(W, x, out);
}